// Round 1
// 185.977 us; speedup vs baseline: 1.0377x; 1.0377x over previous
//
#include <hip/hip_runtime.h>

// PatchesCreate: images [B=64, H=384, W=384, C=3] f32 (NHWC) ->
// patches [B, 576, 768] f32, P=16, G=24.
//
// Slab decomposition: for fixed (b, gy), input rows [gy*16, gy*16+16) are a
// contiguous 72 KiB block AND output patches [gy*24, gy*24+24) are a
// contiguous 72 KiB block. The op is an in-slab permutation of 192 B chunks:
// [py][gx][k] -> [gx][py][k].  We stage HALF a slab (8 rows, 36 KiB) in LDS
// per workgroup so BOTH global streams are long-sequential (copy-ubench-like),
// instead of the previous version's 192B-granule strided reads (4.69 TB/s).
//
// Load phase : 9 contiguous nontemporal float4 loads/thread (36 KiB/WG run).
// Store phase: LDS gather in output order; stores are 24 runs of 1536 B/WG,
//              fully lane-contiguous.
// LDS row stride padded +1 float4 so the gather phase (py varies across
// lanes at fixed bank base) spreads across banks. LDS BW is not on the
// critical path regardless (69 TB/s >> 6.3 TB/s needed).

typedef float f4 __attribute__((ext_vector_type(4)));

constexpr int C     = 3;
constexpr int P     = 16;
constexpr int G     = 24;                 // 384/16
constexpr int ROW4  = 384 * C / 4;        // 288 float4 per image row
constexpr int IMG4  = 384 * ROW4;         // 110592 float4 per image (in == out)
constexpr int HR    = 8;                  // image rows staged per workgroup
constexpr int TILE4 = HR * ROW4;          // 2304 float4 = 36 KiB per tile
constexpr int LSTR  = ROW4 + 1;           // 289: +16 B pad per LDS row
constexpr int BLOCK = 256;
constexpr int PT    = TILE4 / BLOCK;      // 9 float4 per thread (exact)
constexpr int NSLAB = 64 * G * 2;         // 3072 workgroups

constexpr int GY4   = G * P * P * C / 4;  // 4608 f4 per gy-group of patches
constexpr int HALF4 = HR * P * C / 4;     // 96 f4: half-patch offset

__global__ __launch_bounds__(BLOCK)
void patches_kernel(const f4* __restrict__ in, f4* __restrict__ out) {
    __shared__ f4 lds[HR * LSTR];         // 8*289*16 = 36,992 B

    const int s    = blockIdx.x;          // (b*24 + gy)*2 + half
    const int half = s & 1;
    const int bg   = s >> 1;
    const int gy   = bg % G;
    const int b    = bg / G;
    const int t    = threadIdx.x;

    const int in_base  = b * IMG4 + (gy * P + half * HR) * ROW4;
    const int out_base = b * IMG4 + gy * GY4 + half * HALF4;

    // ---- load: contiguous 36 KiB, register-staged (all loads issued first)
    f4 v[PT];
#pragma unroll
    for (int j = 0; j < PT; ++j)
        v[j] = __builtin_nontemporal_load(in + in_base + t + j * BLOCK);

#pragma unroll
    for (int j = 0; j < PT; ++j) {
        int i   = t + j * BLOCK;
        int row = i / ROW4;               // py_local 0..7
        int col = i - row * ROW4;         // 0..287
        lds[row * LSTR + col] = v[j];
    }
    __syncthreads();

    // ---- store: output order [gx][py][k]; gather from LDS [py][gx*12+k]
#pragma unroll
    for (int j = 0; j < PT; ++j) {
        int o  = t + j * BLOCK;           // 0..2303, output f4 within half-slab
        int gx = o / 96;                  // 0..23
        int w  = o - gx * 96;             // 0..95 = py*12 + k
        int py = w / 12;
        int k  = w - py * 12;
        f4 u = lds[py * LSTR + gx * 12 + k];
        __builtin_nontemporal_store(u, out + out_base + gx * 192 + w);
    }
}

extern "C" void kernel_launch(void* const* d_in, const int* in_sizes, int n_in,
                              void* d_out, int out_size, void* d_ws, size_t ws_size,
                              hipStream_t stream) {
    const f4* in  = (const f4*)d_in[0];
    f4*       out = (f4*)d_out;
    patches_kernel<<<NSLAB, BLOCK, 0, stream>>>(in, out);
}

// Round 2
// 184.777 us; speedup vs baseline: 1.0445x; 1.0065x over previous
//
#include <hip/hip_runtime.h>

// PatchesCreate: images [B=64, H=384, W=384, C=3] f32 (NHWC) ->
// patches [B, 576, 768] f32, P=16, G=24.
//
// Persistent software-pipelined LDS permutation.
//
// For fixed (b, gy, half): input rows are a contiguous 36 KiB block and the
// corresponding output half-patches are a contiguous 36 KiB block; the op is
// a [py][gx][k] -> [gx][py][k] permutation of 192 B chunks. Both global
// streams are long-sequential (copy-ubench-like).
//
// v2 (186 us) exposed full load latency per tile: __syncthreads() drains
// vmcnt(0) (the m97 barrier-drain stall), and each one-shot WG alternates a
// pure-read phase with a pure-write phase. v3 fixes both:
//   * grid = 1024 = exactly 4 resident WGs/CU (LDS 36,992 B each), each WG
//     loops over 3 half-slabs -> persistent, zero launch churn;
//   * tile i+1 is prefetched into registers BEFORE tile i's barriers;
//   * raw __builtin_amdgcn_s_barrier() (no implicit vmcnt drain) + manual
//     lgkmcnt(0); the compiler's precise use-def vmcnt waits then leave the
//     9 prefetch loads + 9 stores in flight across both barriers.
// Sync audit: ds_read results are consumed by stores before the top barrier
// (store issue forces lgkm wait), so the top barrier alone protects the LDS
// overwrite (WAR); lgkmcnt(0)+barrier orders ds_write -> other-wave ds_read.

typedef float f4 __attribute__((ext_vector_type(4)));

constexpr int C     = 3;
constexpr int P     = 16;
constexpr int G     = 24;                 // 384/16
constexpr int ROW4  = 384 * C / 4;        // 288 float4 per image row
constexpr int IMG4  = 384 * ROW4;         // 110592 float4 per image (in == out)
constexpr int HR    = 8;                  // image rows staged per tile
constexpr int TILE4 = HR * ROW4;          // 2304 float4 = 36 KiB
constexpr int LSTR  = ROW4 + 1;           // 289: +16 B pad per LDS row
constexpr int BLOCK = 256;
constexpr int PT    = TILE4 / BLOCK;      // 9 float4 per thread (exact)
constexpr int NSLAB = 64 * G * 2;         // 3072 half-slabs
constexpr int GRID  = 1024;               // 4 WGs/CU resident, persistent
constexpr int NITER = NSLAB / GRID;       // 3 tiles per WG

constexpr int GY4   = G * P * P * C / 4;  // 4608 f4 per gy-group of patches
constexpr int HALF4 = HR * P * C / 4;     // 96 f4: half-patch offset

__device__ __forceinline__ int in_base_of(int s) {
    int half = s & 1, bg = s >> 1;
    int gy = bg % G, b = bg / G;
    return b * IMG4 + (gy * P + half * HR) * ROW4;
}
__device__ __forceinline__ int out_base_of(int s) {
    int half = s & 1, bg = s >> 1;
    int gy = bg % G, b = bg / G;
    return b * IMG4 + gy * GY4 + half * HALF4;
}

__global__ __launch_bounds__(BLOCK, 4)
void patches_kernel(const f4* __restrict__ in, f4* __restrict__ out) {
    __shared__ f4 lds[HR * LSTR];         // 36,992 B -> 4 WGs/CU
    const int t  = threadIdx.x;
    const int s0 = blockIdx.x;

    f4 v[PT], u[PT];
    {
        const f4* p = in + in_base_of(s0) + t;
#pragma unroll
        for (int j = 0; j < PT; ++j)
            v[j] = __builtin_nontemporal_load(p + j * BLOCK);
    }

#pragma unroll
    for (int i = 0; i < NITER; ++i) {
        // ---- prefetch tile i+1 into registers (stays in flight all iter)
        if (i + 1 < NITER) {
            const f4* p = in + in_base_of(s0 + (i + 1) * GRID) + t;
#pragma unroll
            for (int j = 0; j < PT; ++j)
                u[j] = __builtin_nontemporal_load(p + j * BLOCK);
            __builtin_amdgcn_sched_barrier(0);   // pin load issue above barriers
        }

        if (i > 0)
            __builtin_amdgcn_s_barrier();  // WAR: all waves done reading prev tile

        // ---- ds_write v (compiler waits precisely for v's loads, not u's)
#pragma unroll
        for (int j = 0; j < PT; ++j) {
            int idx = t + j * BLOCK;
            int row = idx / ROW4;          // 0..7
            int col = idx - row * ROW4;    // 0..287
            lds[row * LSTR + col] = v[j];
        }
        asm volatile("s_waitcnt lgkmcnt(0)" ::: "memory");
        __builtin_amdgcn_s_barrier();      // tile i visible to all waves

        // ---- gather in output order, coalesced nt stores
        const int ob = out_base_of(s0 + i * GRID);
#pragma unroll
        for (int j = 0; j < PT; ++j) {
            int o  = t + j * BLOCK;        // 0..2303
            int gx = o / 96;               // 0..23
            int w  = o - gx * 96;          // py*12 + k
            int py = w / 12;
            int k  = w - py * 12;
            f4 x = lds[py * LSTR + gx * 12 + k];
            __builtin_nontemporal_store(x, out + ob + gx * 192 + w);
        }

        if (i + 1 < NITER) {
#pragma unroll
            for (int j = 0; j < PT; ++j) v[j] = u[j];
        }
    }
}

extern "C" void kernel_launch(void* const* d_in, const int* in_sizes, int n_in,
                              void* d_out, int out_size, void* d_ws, size_t ws_size,
                              hipStream_t stream) {
    const f4* in  = (const f4*)d_in[0];
    f4*       out = (f4*)d_out;
    patches_kernel<<<GRID, BLOCK, 0, stream>>>(in, out);
}